// Round 1
// baseline (313.545 us; speedup 1.0000x reference)
//
#include <hip/hip_runtime.h>

// Problem constants (fixed by setup_inputs).
#define Bn   8
#define Cn   256
#define MIDn 16
#define Hn   128
#define Wn   128
#define HWn  (Hn * Wn)      // 16384

// ---------------------------------------------------------------------------
// Kernel 1: 1x1 reduce  x(B,C,H,W) x w_reduce(MID,C) -> xlow(B,MID,H,W)
// 512 blocks x 256 threads, one pixel per thread, loop over C.
// Weight index m*Cn+c is lane-uniform -> scalar loads (s_load), no LDS needed.
// ---------------------------------------------------------------------------
__global__ __launch_bounds__(256) void reduce_k(const float* __restrict__ x,
                                                const float* __restrict__ wr,
                                                float* __restrict__ xlow) {
    const int tid = threadIdx.x;
    const int b   = blockIdx.x >> 6;                  // 64 blocks per batch
    const int hw  = ((blockIdx.x & 63) << 8) + tid;   // pixel within batch

    const float* xb = x + (size_t)b * Cn * HWn + hw;

    float acc[MIDn];
#pragma unroll
    for (int m = 0; m < MIDn; ++m) acc[m] = 0.f;

#pragma unroll 4
    for (int c = 0; c < Cn; ++c) {
        const float v = xb[(size_t)c * HWn];          // coalesced 256 B / wave
#pragma unroll
        for (int m = 0; m < MIDn; ++m)
            acc[m] = fmaf(v, wr[m * Cn + c], acc[m]); // wr uniform -> SGPR
    }

    float* ob = xlow + (size_t)b * MIDn * HWn + hw;
#pragma unroll
    for (int m = 0; m < MIDn; ++m) ob[m * HWn] = acc[m];
}

// ---------------------------------------------------------------------------
// Kernel 2: per-pixel blended separable-basis 7x7 conv + 1x1 expand, fused.
// BASE_H[i][j] = u[i]*v[j], BASE_V[i][j] = v[i]*u[j]  (u: sigma=2.5, v: sigma=1)
// combined[i][j] = wh*BASE_H + (1-wh)*BASE_V, wh = cos(angle)^2  (per pixel).
// Tile 32x8 pixels per 256-thread block; halo tile in LDS (reflect-padded).
// ---------------------------------------------------------------------------
#define TW 32
#define TH 8
#define HR (TH + 6)   // 14
#define WR (TW + 6)   // 38

__device__ __forceinline__ int reflect_i(int i, int n) {
    return i < 0 ? -i : (i >= n ? 2 * n - 2 - i : i);
}

__global__ __launch_bounds__(256) void conv_expand_k(const float* __restrict__ xlow,
                                                     const float* __restrict__ ang,
                                                     const float* __restrict__ we,
                                                     float* __restrict__ out) {
    __shared__ float tile[MIDn][HR][WR];   // 16*14*38*4 B = 34 KB

    const int tid = threadIdx.x;
    const int bx  = blockIdx.x;
    const int b   = bx >> 6;               // 64 tiles per batch (16 x 4)
    const int rem = bx & 63;
    const int th0 = (rem >> 2) * TH;
    const int tw0 = (rem & 3) * TW;

    // ---- stage halo tile (reflect-indexed) ----
    const float* xb = xlow + (size_t)b * MIDn * HWn;
    for (int idx = tid; idx < MIDn * HR * WR; idx += 256) {
        const int m  = idx / (HR * WR);
        const int r2 = idx - m * (HR * WR);
        const int r  = r2 / WR;
        const int cc = r2 - r * WR;
        const int gr = reflect_i(th0 + r - 3, Hn);
        const int gc = reflect_i(tw0 + cc - 3, Wn);
        tile[m][r][cc] = xb[m * HWn + gr * Wn + gc];
    }
    __syncthreads();

    const int pc = tid & (TW - 1);
    const int pr = tid >> 5;
    const int gh = th0 + pr;
    const int gw = tw0 + pc;

    // ---- per-pixel blended 7x7 weights (compile-time constant basis) ----
    const float a  = ang[b * HWn + gh * Wn + gw];
    const float ch = cosf(a);
    const float wh = ch * ch;

    // raw gaussians: u = exp(-d^2/12.5), v = exp(-d^2/2), d = dist from center
    const float fu[7] = {0.48675226f, 0.72614904f, 0.92311635f, 1.0f,
                         0.92311635f, 0.72614904f, 0.48675226f};
    const float fv[7] = {0.011108997f, 0.13533528f, 0.60653066f, 1.0f,
                         0.60653066f, 0.13533528f, 0.011108997f};
    const float su = 1.f + 2.f * (0.48675226f + 0.72614904f + 0.92311635f);
    const float sv = 1.f + 2.f * (0.011108997f + 0.13533528f + 0.60653066f);
    const float inv = 1.f / (su * sv + 1e-8f);        // matches ker.sum()+1e-8
    const float aH = wh * inv;
    const float aV = (1.f - wh) * inv;

    float wcomb[49];
#pragma unroll
    for (int i = 0; i < 7; ++i)
#pragma unroll
        for (int j = 0; j < 7; ++j)
            wcomb[i * 7 + j] = aH * (fu[i] * fv[j]) + aV * (fv[i] * fu[j]);

    // ---- conv: 16 mids x 49 taps, all unrolled (taps from LDS) ----
    float ol[MIDn];
#pragma unroll
    for (int m = 0; m < MIDn; ++m) {
        float acc = 0.f;
#pragma unroll
        for (int i = 0; i < 7; ++i)
#pragma unroll
            for (int j = 0; j < 7; ++j)
                acc = fmaf(wcomb[i * 7 + j], tile[m][pr + i][pc + j], acc);
        ol[m] = acc;
    }

    // ---- expand: 256 outputs per pixel; we[c*16+m] lane-uniform -> s_load ----
    float* ob = out + (size_t)b * Cn * HWn + gh * Wn + gw;
#pragma unroll 4
    for (int c = 0; c < Cn; ++c) {
        float o = 0.f;
#pragma unroll
        for (int m = 0; m < MIDn; ++m)
            o = fmaf(we[c * MIDn + m], ol[m], o);
        ob[(size_t)c * HWn] = o;                      // coalesced per c
    }
}

// ---------------------------------------------------------------------------
extern "C" void kernel_launch(void* const* d_in, const int* in_sizes, int n_in,
                              void* d_out, int out_size, void* d_ws, size_t ws_size,
                              hipStream_t stream) {
    const float* x   = (const float*)d_in[0];  // (8,256,128,128)
    const float* ang = (const float*)d_in[1];  // (8,128,128)
    const float* wr  = (const float*)d_in[2];  // (16,256)
    const float* we  = (const float*)d_in[3];  // (256,16)
    float*       out = (float*)d_out;          // (8,256,128,128)
    float*       xlo = (float*)d_ws;           // scratch: 8 MiB (B,MID,H,W)

    reduce_k<<<dim3(512), dim3(256), 0, stream>>>(x, wr, xlo);
    conv_expand_k<<<dim3(512), dim3(256), 0, stream>>>(xlo, ang, we, out);
}

// Round 2
// 303.969 us; speedup vs baseline: 1.0315x; 1.0315x over previous
//
#include <hip/hip_runtime.h>

// Problem constants (fixed by setup_inputs).
#define Bn   8
#define Cn   256
#define MIDn 16
#define Hn   128
#define Wn   128
#define HWn  (Hn * Wn)      // 16384

// ---------------------------------------------------------------------------
// K1: partial 1x1 reduce. Grid (64 pixel-blocks, nch c-chunks, 8 batches).
// Each block: 256 pixels (1/thread), 256/nch channels -> partial accumulator.
// nch=4 -> 2048 blocks = 8 blocks/CU = 32 waves/CU (vs 2 blocks/CU before).
// ---------------------------------------------------------------------------
__global__ __launch_bounds__(256) void reduce_part_k(const float* __restrict__ x,
                                                     const float* __restrict__ wr,
                                                     float* __restrict__ part,
                                                     int cper) {
    const int tid = threadIdx.x;
    const int hw  = blockIdx.x * 256 + tid;
    const int t   = blockIdx.y;                 // channel chunk
    const int b   = blockIdx.z;
    const int c0  = t * cper;

    const float* xb = x + (size_t)b * Cn * HWn + (size_t)c0 * HWn + hw;

    float acc[MIDn];
#pragma unroll
    for (int m = 0; m < MIDn; ++m) acc[m] = 0.f;

#pragma unroll 8
    for (int c = 0; c < cper; ++c) {
        const float v = xb[(size_t)c * HWn];    // coalesced 256 B / wave
        const float* w = wr + (c0 + c);         // lane-uniform -> s_load
#pragma unroll
        for (int m = 0; m < MIDn; ++m)
            acc[m] = fmaf(v, w[m * Cn], acc[m]);
    }

    float* ob = part + ((size_t)t * Bn + b) * MIDn * HWn + hw;
#pragma unroll
    for (int m = 0; m < MIDn; ++m) ob[m * HWn] = acc[m];
}

// ---------------------------------------------------------------------------
// K2: blended separable-basis 7x7 conv. Sums the nch partials during staging.
// Split over mid-halves (blockIdx.y: 8 mids each) -> 1024 blocks, 17 KB LDS.
// Writes out_low (B,MID,H,W) fp32.
// ---------------------------------------------------------------------------
#define TW 32
#define TH 8
#define HR (TH + 6)   // 14
#define WR (TW + 6)   // 38
#define MH 8          // mids per block

__device__ __forceinline__ int reflect_i(int i, int n) {
    return i < 0 ? -i : (i >= n ? 2 * n - 2 - i : i);
}

__global__ __launch_bounds__(256) void conv_k(const float* __restrict__ part,
                                              const float* __restrict__ ang,
                                              float* __restrict__ xlow2,
                                              int nch) {
    __shared__ float tile[MH][HR][WR];   // 8*14*38*4 B = 17 KB

    const int tid = threadIdx.x;
    const int b   = blockIdx.z;
    const int m0  = blockIdx.y * MH;
    const int rem = blockIdx.x;          // 0..63 -> 16 x 4 tiles
    const int th0 = (rem >> 2) * TH;
    const int tw0 = (rem & 3) * TW;

    const size_t chunkF = (size_t)Bn * MIDn * HWn;
    const float* pb = part + (size_t)b * MIDn * HWn + (size_t)m0 * HWn;

    // ---- stage halo tile, summing nch partial buffers ----
    for (int idx = tid; idx < MH * HR * WR; idx += 256) {
        const int m  = idx / (HR * WR);
        const int r2 = idx - m * (HR * WR);
        const int r  = r2 / WR;
        const int cc = r2 - r * WR;
        const int gr = reflect_i(th0 + r - 3, Hn);
        const int gc = reflect_i(tw0 + cc - 3, Wn);
        const size_t off = (size_t)m * HWn + gr * Wn + gc;
        float s = pb[off];
        for (int t = 1; t < nch; ++t) s += pb[(size_t)t * chunkF + off];
        tile[m][r][cc] = s;
    }
    __syncthreads();

    const int pc = tid & (TW - 1);
    const int pr = tid >> 5;
    const int gh = th0 + pr;
    const int gw = tw0 + pc;

    // ---- per-pixel blended 7x7 weights (compile-time constant basis) ----
    const float a  = ang[b * HWn + gh * Wn + gw];
    const float ch = cosf(a);
    const float wh = ch * ch;

    const float fu[7] = {0.48675226f, 0.72614904f, 0.92311635f, 1.0f,
                         0.92311635f, 0.72614904f, 0.48675226f};
    const float fv[7] = {0.011108997f, 0.13533528f, 0.60653066f, 1.0f,
                         0.60653066f, 0.13533528f, 0.011108997f};
    const float su = 1.f + 2.f * (0.48675226f + 0.72614904f + 0.92311635f);
    const float sv = 1.f + 2.f * (0.011108997f + 0.13533528f + 0.60653066f);
    const float inv = 1.f / (su * sv + 1e-8f);        // matches ker.sum()+1e-8
    const float aH = wh * inv;
    const float aV = (1.f - wh) * inv;

    float wcomb[49];
#pragma unroll
    for (int i = 0; i < 7; ++i)
#pragma unroll
        for (int j = 0; j < 7; ++j)
            wcomb[i * 7 + j] = aH * (fu[i] * fv[j]) + aV * (fv[i] * fu[j]);

    // ---- conv: MH mids x 49 taps, fully unrolled (taps from LDS) ----
    float* ob = xlow2 + (size_t)b * MIDn * HWn + (size_t)m0 * HWn + gh * Wn + gw;
#pragma unroll
    for (int m = 0; m < MH; ++m) {
        float acc = 0.f;
#pragma unroll
        for (int i = 0; i < 7; ++i)
#pragma unroll
            for (int j = 0; j < 7; ++j)
                acc = fmaf(wcomb[i * 7 + j], tile[m][pr + i][pc + j], acc);
        ob[(size_t)m * HWn] = acc;
    }
}

// ---------------------------------------------------------------------------
// K3: 1x1 expand (16 -> 256), c split x4 -> 2048 blocks, write-BW bound.
// ---------------------------------------------------------------------------
__global__ __launch_bounds__(256) void expand_k(const float* __restrict__ xlow2,
                                                const float* __restrict__ we,
                                                float* __restrict__ out) {
    const int tid = threadIdx.x;
    const int hw  = blockIdx.x * 256 + tid;
    const int c0  = blockIdx.y * 64;
    const int b   = blockIdx.z;

    const float* xb = xlow2 + (size_t)b * MIDn * HWn + hw;
    float ol[MIDn];
#pragma unroll
    for (int m = 0; m < MIDn; ++m) ol[m] = xb[(size_t)m * HWn];

    float* ob = out + (size_t)b * Cn * HWn + (size_t)c0 * HWn + hw;
#pragma unroll 8
    for (int ci = 0; ci < 64; ++ci) {
        const float* w = we + (size_t)(c0 + ci) * MIDn;   // lane-uniform -> s_load
        float o = 0.f;
#pragma unroll
        for (int m = 0; m < MIDn; ++m)
            o = fmaf(w[m], ol[m], o);
        ob[(size_t)ci * HWn] = o;                         // coalesced per c
    }
}

// ---------------------------------------------------------------------------
extern "C" void kernel_launch(void* const* d_in, const int* in_sizes, int n_in,
                              void* d_out, int out_size, void* d_ws, size_t ws_size,
                              hipStream_t stream) {
    const float* x   = (const float*)d_in[0];  // (8,256,128,128)
    const float* ang = (const float*)d_in[1];  // (8,128,128)
    const float* wr  = (const float*)d_in[2];  // (16,256)
    const float* we  = (const float*)d_in[3];  // (256,16)
    float*       out = (float*)d_out;          // (8,256,128,128)

    const size_t chunkB = (size_t)Bn * MIDn * HWn * sizeof(float);  // 8 MiB
    // nch partial buffers + out_low must fit in ws; fall back to nch=1.
    const int nch = (ws_size >= 5 * chunkB) ? 4 : 1;
    float* part  = (float*)d_ws;
    float* xlow2 = (float*)((char*)d_ws + (size_t)nch * chunkB);

    reduce_part_k<<<dim3(64, nch, Bn), dim3(256), 0, stream>>>(x, wr, part, Cn / nch);
    conv_k<<<dim3(64, MIDn / MH, Bn), dim3(256), 0, stream>>>(part, ang, xlow2, nch);
    expand_k<<<dim3(64, Cn / 64, Bn), dim3(256), 0, stream>>>(xlow2, we, out);
}

// Round 3
// 285.179 us; speedup vs baseline: 1.0995x; 1.0659x over previous
//
#include <hip/hip_runtime.h>

// Problem constants (fixed by setup_inputs).
#define Bn   8
#define Cn   256
#define MIDn 16
#define Hn   128
#define Wn   128
#define HWn  (Hn * Wn)      // 16384

// ---------------------------------------------------------------------------
// K1: partial 1x1 reduce, float2-vectorized (8 B/lane).
// Grid (32 px-blocks, nch c-chunks, 8 batches) = 1024 blocks (4/CU).
// Each thread: 2 consecutive pixels, cper channels -> partial accumulators.
// ---------------------------------------------------------------------------
__global__ __launch_bounds__(256) void reduce_part_k(const float2* __restrict__ x2,
                                                     const float* __restrict__ wr,
                                                     float2* __restrict__ part2,
                                                     int cper) {
    const int tid = threadIdx.x;
    const int p   = blockIdx.x * 256 + tid;     // float2 index within batch
    const int t   = blockIdx.y;                 // channel chunk
    const int b   = blockIdx.z;
    const int c0  = t * cper;

    const float2* xb = x2 + ((size_t)b * Cn + c0) * (HWn / 2) + p;

    float2 acc[MIDn];
#pragma unroll
    for (int m = 0; m < MIDn; ++m) acc[m] = make_float2(0.f, 0.f);

#pragma unroll 8
    for (int c = 0; c < cper; ++c) {
        const float2 v = xb[(size_t)c * (HWn / 2)];   // 512 B / wave
        const float* w = wr + (c0 + c);               // lane-uniform -> s_load
#pragma unroll
        for (int m = 0; m < MIDn; ++m) {
            const float wm = w[m * Cn];
            acc[m].x = fmaf(v.x, wm, acc[m].x);
            acc[m].y = fmaf(v.y, wm, acc[m].y);
        }
    }

    float2* ob = part2 + ((size_t)t * Bn + b) * MIDn * (HWn / 2) + p;
#pragma unroll
    for (int m = 0; m < MIDn; ++m) ob[(size_t)m * (HWn / 2)] = acc[m];
}

// ---------------------------------------------------------------------------
// K2: blended separable-basis 7x7 conv. Sums nch partials during staging.
// MH=4 mids/block -> LDS 8.5 KB, grid (64,4,8)=2048 blocks = 8 blocks/CU
// (32 waves/CU: latency-hiding for the 196 ds_read+FMA chain per thread).
// ---------------------------------------------------------------------------
#define TW 32
#define TH 8
#define HR (TH + 6)   // 14
#define WR (TW + 6)   // 38
#define MH 4          // mids per block

__device__ __forceinline__ int reflect_i(int i, int n) {
    return i < 0 ? -i : (i >= n ? 2 * n - 2 - i : i);
}

__global__ __launch_bounds__(256) void conv_k(const float* __restrict__ part,
                                              const float* __restrict__ ang,
                                              float* __restrict__ xlow2,
                                              int nch) {
    __shared__ float tile[MH][HR][WR];   // 4*14*38*4 B = 8.5 KB

    const int tid = threadIdx.x;
    const int b   = blockIdx.z;
    const int m0  = blockIdx.y * MH;
    const int rem = blockIdx.x;          // 0..63 -> 16 x 4 tiles
    const int th0 = (rem >> 2) * TH;
    const int tw0 = (rem & 3) * TW;

    const size_t chunkF = (size_t)Bn * MIDn * HWn;
    const float* pb = part + (size_t)b * MIDn * HWn + (size_t)m0 * HWn;

    // ---- stage halo tile (reflect-indexed), summing nch partial buffers ----
    for (int idx = tid; idx < MH * HR * WR; idx += 256) {
        const int m  = idx / (HR * WR);
        const int r2 = idx - m * (HR * WR);
        const int r  = r2 / WR;
        const int cc = r2 - r * WR;
        const int gr = reflect_i(th0 + r - 3, Hn);
        const int gc = reflect_i(tw0 + cc - 3, Wn);
        const size_t off = (size_t)m * HWn + gr * Wn + gc;
        float s = pb[off];
        for (int t = 1; t < nch; ++t) s += pb[(size_t)t * chunkF + off];
        tile[m][r][cc] = s;
    }
    __syncthreads();

    const int pc = tid & (TW - 1);
    const int pr = tid >> 5;
    const int gh = th0 + pr;
    const int gw = tw0 + pc;

    // ---- per-pixel blended 7x7 weights (compile-time constant basis) ----
    const float a  = ang[b * HWn + gh * Wn + gw];
    const float ch = cosf(a);
    const float wh = ch * ch;

    const float fu[7] = {0.48675226f, 0.72614904f, 0.92311635f, 1.0f,
                         0.92311635f, 0.72614904f, 0.48675226f};
    const float fv[7] = {0.011108997f, 0.13533528f, 0.60653066f, 1.0f,
                         0.60653066f, 0.13533528f, 0.011108997f};
    const float su = 1.f + 2.f * (0.48675226f + 0.72614904f + 0.92311635f);
    const float sv = 1.f + 2.f * (0.011108997f + 0.13533528f + 0.60653066f);
    const float inv = 1.f / (su * sv + 1e-8f);        // matches ker.sum()+1e-8
    const float aH = wh * inv;
    const float aV = (1.f - wh) * inv;

    float wcomb[49];
#pragma unroll
    for (int i = 0; i < 7; ++i)
#pragma unroll
        for (int j = 0; j < 7; ++j)
            wcomb[i * 7 + j] = aH * (fu[i] * fv[j]) + aV * (fv[i] * fu[j]);

    // ---- conv: MH mids x 49 taps, fully unrolled (taps from LDS) ----
    float* ob = xlow2 + (size_t)b * MIDn * HWn + (size_t)m0 * HWn + gh * Wn + gw;
#pragma unroll
    for (int m = 0; m < MH; ++m) {
        float acc = 0.f;
#pragma unroll
        for (int i = 0; i < 7; ++i)
#pragma unroll
            for (int j = 0; j < 7; ++j)
                acc = fmaf(wcomb[i * 7 + j], tile[m][pr + i][pc + j], acc);
        ob[(size_t)m * HWn] = acc;
    }
}

// ---------------------------------------------------------------------------
// K3: 1x1 expand (16 -> 256), float2 stores, c split x4.
// Grid (32,4,8) = 1024 blocks (4/CU). Stores 512 B/wave per c.
// ---------------------------------------------------------------------------
__global__ __launch_bounds__(256) void expand_k(const float2* __restrict__ xlow22,
                                                const float* __restrict__ we,
                                                float2* __restrict__ out2) {
    const int tid = threadIdx.x;
    const int p   = blockIdx.x * 256 + tid;   // float2 index within batch
    const int c0  = blockIdx.y * 64;
    const int b   = blockIdx.z;

    const float2* xb = xlow22 + (size_t)b * MIDn * (HWn / 2) + p;
    float2 ol[MIDn];
#pragma unroll
    for (int m = 0; m < MIDn; ++m) ol[m] = xb[(size_t)m * (HWn / 2)];

    float2* ob = out2 + ((size_t)b * Cn + c0) * (HWn / 2) + p;
#pragma unroll 4
    for (int ci = 0; ci < 64; ++ci) {
        const float* w = we + (size_t)(c0 + ci) * MIDn;   // lane-uniform -> s_load
        float2 o = make_float2(0.f, 0.f);
#pragma unroll
        for (int m = 0; m < MIDn; ++m) {
            o.x = fmaf(w[m], ol[m].x, o.x);
            o.y = fmaf(w[m], ol[m].y, o.y);
        }
        ob[(size_t)ci * (HWn / 2)] = o;                   // coalesced per c
    }
}

// ---------------------------------------------------------------------------
extern "C" void kernel_launch(void* const* d_in, const int* in_sizes, int n_in,
                              void* d_out, int out_size, void* d_ws, size_t ws_size,
                              hipStream_t stream) {
    const float* x   = (const float*)d_in[0];  // (8,256,128,128)
    const float* ang = (const float*)d_in[1];  // (8,128,128)
    const float* wr  = (const float*)d_in[2];  // (16,256)
    const float* we  = (const float*)d_in[3];  // (256,16)
    float*       out = (float*)d_out;          // (8,256,128,128)

    const size_t chunkB = (size_t)Bn * MIDn * HWn * sizeof(float);  // 8 MiB
    const int nch = (ws_size >= 5 * chunkB) ? 4 : 1;
    float* part  = (float*)d_ws;
    float* xlow2 = (float*)((char*)d_ws + (size_t)nch * chunkB);

    reduce_part_k<<<dim3(32, nch, Bn), dim3(256), 0, stream>>>(
        (const float2*)x, wr, (float2*)part, Cn / nch);
    conv_k<<<dim3(64, MIDn / MH, Bn), dim3(256), 0, stream>>>(part, ang, xlow2, nch);
    expand_k<<<dim3(32, Cn / 64, Bn), dim3(256), 0, stream>>>(
        (const float2*)xlow2, we, (float2*)out);
}